// Round 11
// baseline (2684.628 us; speedup 1.0000x reference)
//
#include <hip/hip_runtime.h>

typedef unsigned short u16;
typedef unsigned int u32;
typedef unsigned long long u64;

#define NBLK 256

__device__ __forceinline__ float b2f(u16 u) {
    u32 i = ((u32)u) << 16;
    return __builtin_bit_cast(float, i);
}
__device__ __forceinline__ u16 f2b(float f) {
    u32 b = __builtin_bit_cast(u32, f);
    b += 0x7FFFu + ((b >> 16) & 1u);   // RNE
    return (u16)(b >> 16);
}
__device__ __forceinline__ float sigm(float x) {
    return 1.f / (1.f + __expf(-x));
}
__device__ __forceinline__ float tanh_fast(float x) {
    float a = fabsf(x);
    float e = __expf(-2.f * a);            // in (0,1], never inf
    float r = (1.f - e) / (1.f + e);
    return copysignf(r, x);
}

// ---------------------------------------------------------------------------
// Single persistent kernel. 256 WGs x 512 thr, 1 WG/CU.
// PROLOGUE (once): block wg stages its 32 Wih rows in LDS (per phase) and
//   computes its whole Xp slice [514][32] into LDS (~17 MFLOP, all 8 waves).
//   No Xp in global, no separate launch, W read exactly once.
// MAIN LOOP (= round-8 body): Whh in fp32 registers w[4][32]; h exchange
//   bf16-packed data-is-the-flag (poll hseqB[t-1] vs 0xFFFF sentinel);
//   xp read from LDS; tail on wave 0; h store lanes 0-3 (16B coalesced).
// ---------------------------------------------------------------------------
__global__ void __launch_bounds__(512, 1)
rnn_coop(const float* __restrict__ WhhA, const float* __restrict__ WhhB,
         const float* __restrict__ pWih, const float* __restrict__ pWhh,
         const float* __restrict__ pB,
         const float* __restrict__ inWih, const float* __restrict__ outWih,
         const float* __restrict__ in_b, const float* __restrict__ out_b,
         const float* __restrict__ embed, const float* __restrict__ eos,
         const int* __restrict__ in_seq, const int* __restrict__ out_seq,
         u32* __restrict__ hseqB, float* __restrict__ out)
{
    __shared__ __align__(16) float wihS[32 * 512];   // 64KB Wih slice (A then B)
    __shared__ __align__(16) float xs[8][512];       // 16KB x-rows staging
    __shared__ __align__(16) float XpLds[514 * 32];  // 64.2KB Xp slice
    __shared__ __align__(16) float hs[2048];         // 8KB staged fp32 h
    __shared__ float biasS[2][32], gsum[32];

    const int wg = blockIdx.x;
    const int tid = threadIdx.x;
    const int lane = tid & 63;
    const int wv = tid >> 6;

    if (tid < 32) {
        int gofs = ((tid >> 3) << 11) + (wg << 3) + (tid & 7);
        biasS[0][tid] = in_b[gofs];
        biasS[1][tid] = out_b[gofs];
        gsum[tid] = 0.f;
    }

    // ================= PROLOGUE: Xp slice into LDS =================
    for (int p = 0; p < 2; ++p) {
        const float* Wih = p ? outWih : inWih;
        const int*   sq  = p ? out_seq : in_seq;
        __syncthreads();                       // wihS reuse safe
        for (int idx = tid; idx < 4096; idx += 512) {
            int m = idx >> 7, c4 = (idx & 127) << 2;   // m = g*8+j
            size_t grow = (size_t)(((m >> 3) << 11) + (wg << 3) + (m & 7)) * 512;
            *(float4*)&wihS[m * 512 + c4] = *(const float4*)&Wih[grow + c4];
        }
        __syncthreads();

        for (int grp = 0; grp < 33; ++grp) {
            const int t0 = grp * 8;
            const int nt = min(8, 257 - t0);
            __syncthreads();                   // xs reuse
            for (int idx = tid; idx < nt * 512; idx += 512) {
                int tt = idx >> 9, col = idx & 511;
                int tk = t0 + tt;
                xs[tt][col] = (tk < 256) ? embed[(size_t)sq[tk] * 512 + col]
                                         : eos[col];
            }
            __syncthreads();

#pragma unroll
            for (int half = 0; half < 2; ++half) {
                float xr[4][8];
#pragma unroll
                for (int t4 = 0; t4 < 4; ++t4) {
#pragma unroll
                    for (int q = 0; q < 2; ++q)
                        *(float4*)&xr[t4][q * 4] =
                            *(const float4*)&xs[half * 4 + t4][(q << 8) + (lane << 2)];
                }
#pragma unroll
                for (int rr = 0; rr < 4; ++rr) {
                    const int m = (wv << 2) + rr;
                    float wf[8];
#pragma unroll
                    for (int q = 0; q < 2; ++q)
                        *(float4*)&wf[q * 4] =
                            *(const float4*)&wihS[m * 512 + (q << 8) + (lane << 2)];
                    float acc[4];
#pragma unroll
                    for (int t4 = 0; t4 < 4; ++t4) {
                        float a = 0.f;
#pragma unroll
                        for (int j = 0; j < 8; ++j) a = fmaf(wf[j], xr[t4][j], a);
                        acc[t4] = a;
                    }
#pragma unroll
                    for (int t4 = 0; t4 < 4; ++t4) {
                        float a = acc[t4];
#pragma unroll
                        for (int off = 32; off > 0; off >>= 1)
                            a += __shfl_xor(a, off, 64);
                        const int tt = half * 4 + t4;
                        if (lane == 0 && tt < nt)
                            XpLds[(p * 257 + t0 + tt) * 32 + m] = a + biasS[p][m];
                    }
                }
            }
        }
    }
    // ================= END PROLOGUE =================

    float w[4][32];        // fp32 Whh slice: rows rl=4*wv+rr, 32 cols/lane
    float c_reg = 0.f;     // valid on lanes 0-7 of wave 0
    float xp2 = 0.f;       // phase-2 gate input (pB), wave0 lanes 0-31

    for (int t = 0; t < 524; ++t) {
        const int phase = (t < 257) ? 0 : (t < 514) ? 1 : 2;

        if (t == 0 || t == 257 || t == 514) {
            if (phase < 2) {
                const float* Ws = phase ? WhhB : WhhA;
#pragma unroll
                for (int rr = 0; rr < 4; ++rr) {
                    int rl = (wv << 2) + rr;
                    const float* Wr = Ws + (size_t)(((rl >> 3) << 11) + (wg << 3) + (rl & 7)) * 2048;
#pragma unroll
                    for (int q = 0; q < 8; ++q)
                        *(float4*)&w[rr][q * 4] = *(const float4*)&Wr[(q << 8) + (lane << 2)];
                }
            } else {
#pragma unroll
                for (int rr = 0; rr < 4; ++rr) {
                    int rl = (wv << 2) + rr;
                    size_t off = (size_t)(((rl >> 3) << 11) + (wg << 3) + (rl & 7)) * 2048;
#pragma unroll
                    for (int q = 0; q < 8; ++q) {
                        float4 a = *(const float4*)&pWih[off + (q << 8) + (lane << 2)];
                        float4 b = *(const float4*)&pWhh[off + (q << 8) + (lane << 2)];
                        float4 s;
                        s.x = a.x + b.x; s.y = a.y + b.y;
                        s.z = a.z + b.z; s.w = a.w + b.w;
                        *(float4*)&w[rr][q * 4] = s;
                    }
                }
                if (wv == 0 && lane < 32)
                    xp2 = pB[((lane >> 3) << 11) + (wg << 3) + (lane & 7)];
            }
        }

        if (t > 0) {
            // poll own u64 (4 bf16) of hseqB[t-1]; sentinel 0xFFFF per u16.
            // Producer writes u32 granules, so per-u16 checks are torn-safe.
            const u64* src = (const u64*)hseqB + (size_t)(t - 1) * 512 + tid;
            u64 a = __hip_atomic_load(src, __ATOMIC_RELAXED, __HIP_MEMORY_SCOPE_AGENT);
            while ((u16)a == 0xFFFFu || (u16)(a >> 16) == 0xFFFFu ||
                   (u16)(a >> 32) == 0xFFFFu || (u16)(a >> 48) == 0xFFFFu)
                a = __hip_atomic_load(src, __ATOMIC_RELAXED, __HIP_MEMORY_SCOPE_AGENT);
            float4 hv;
            hv.x = b2f((u16)a);         hv.y = b2f((u16)(a >> 16));
            hv.z = b2f((u16)(a >> 32)); hv.w = b2f((u16)(a >> 48));
            *(float4*)&hs[tid << 2] = hv;       // 16B/lane, conflict-free
        }
        __syncthreads();

        if (t > 0) {
            float a0 = 0.f, a1 = 0.f, a2 = 0.f, a3 = 0.f;
#pragma unroll
            for (int q = 0; q < 8; ++q) {
                float4 hv = *(const float4*)&hs[(q << 8) + (lane << 2)];
#pragma unroll
                for (int j = 0; j < 4; ++j) {
                    float h = ((const float*)&hv)[j];
                    a0 = fmaf(w[0][q * 4 + j], h, a0);
                    a1 = fmaf(w[1][q * 4 + j], h, a1);
                    a2 = fmaf(w[2][q * 4 + j], h, a2);
                    a3 = fmaf(w[3][q * 4 + j], h, a3);
                }
            }
#pragma unroll
            for (int off = 32; off > 0; off >>= 1) {
                a0 += __shfl_xor(a0, off, 64);
                a1 += __shfl_xor(a1, off, 64);
                a2 += __shfl_xor(a2, off, 64);
                a3 += __shfl_xor(a3, off, 64);
            }
            if (lane == 0) {
                const int rl = wv << 2;
                gsum[rl]     = a0;
                gsum[rl + 1] = a1;
                gsum[rl + 2] = a2;
                gsum[rl + 3] = a3;
            }
        }
        __syncthreads();

        if (wv == 0) {
            // 32 parallel activations (lanes 0-31); lanes >=32 compute garbage
            float xpv = (phase < 2) ? XpLds[t * 32 + (lane & 31)] : xp2;
            float tot = xpv + gsum[lane & 31];
            float act = ((lane >> 3) == 2) ? tanh_fast(tot) : sigm(tot);
            const int j = lane & 7;
            float fi = __shfl(act, j, 64);        // gate i
            float ff = __shfl(act, 8 + j, 64);    // gate f
            float fg = __shfl(act, 16 + j, 64);   // gate g~
            float fo = __shfl(act, 24 + j, 64);   // gate o
            c_reg = ff * c_reg + fi * fg;
            float h2 = fo * tanh_fast(c_reg);
            u32 hb = (u32)f2b(h2);
            u32 lo = (u32)__shfl((int)hb, (lane & 3) * 2, 64);
            u32 hi = (u32)__shfl((int)hb, (lane & 3) * 2 + 1, 64);
            if (lane < 4)
                __hip_atomic_store(&hseqB[(size_t)t * 1024 + (wg << 2) + lane],
                                   (hi << 16) | lo,
                                   __ATOMIC_RELAXED, __HIP_MEMORY_SCOPE_AGENT);
            if (phase == 2 && lane < 8)
                out[(size_t)(t - 514) * 2048 + (wg << 3) + lane] = h2;
        }
        // no inter-block barrier: data arrival is the sync
    }
}

// ---------------------------------------------------------------------------
extern "C" void kernel_launch(void* const* d_in, const int* in_sizes, int n_in,
                              void* d_out, int out_size, void* d_ws, size_t ws_size,
                              hipStream_t stream) {
    const int*   in_seq   = (const int*)d_in[0];
    const int*   out_seq  = (const int*)d_in[1];
    const float* embed    = (const float*)d_in[2];
    const float* eos      = (const float*)d_in[3];
    const float* in_Wih   = (const float*)d_in[4];
    const float* in_Whh   = (const float*)d_in[5];
    const float* in_b     = (const float*)d_in[6];
    const float* out_Wih  = (const float*)d_in[7];
    const float* out_Whh  = (const float*)d_in[8];
    const float* out_b    = (const float*)d_in[9];
    const float* pg_Wih   = (const float*)d_in[10];
    const float* pg_Whh   = (const float*)d_in[11];
    const float* pg_b     = (const float*)d_in[12];

    u32* hseqB = (u32*)d_ws;                           // 524*1024 u32 (bf16 x2)

    // bf16 NaN sentinel 0xFFFF; fresh region per step -> no reuse races
    hipMemsetAsync(hseqB, 0xFF, (size_t)524 * 1024 * sizeof(u32), stream);

    float* out = (float*)d_out;
    void* args[] = { (void*)&in_Whh, (void*)&out_Whh, (void*)&pg_Wih, (void*)&pg_Whh,
                     (void*)&pg_b,
                     (void*)&in_Wih, (void*)&out_Wih, (void*)&in_b, (void*)&out_b,
                     (void*)&embed, (void*)&eos, (void*)&in_seq, (void*)&out_seq,
                     (void*)&hseqB, (void*)&out };
    hipLaunchCooperativeKernel((const void*)rnn_coop, dim3(NBLK), dim3(512),
                               args, 0, stream);
}